// Round 6
// baseline (288.171 us; speedup 1.0000x reference)
//
#include <hip/hip_runtime.h>
#include <stdint.h>

#define B  8
#define TE 2048
#define TD 256
#define H  128

// ---------- kernel 1: EgT[b][k][t] = exp(2*(enc@W_a))^T ; FgT[b][k][j] = exp(2*(dec@U_a))^T ----------
__global__ __launch_bounds__(256) void proj_kernel(
    const float* __restrict__ enc, const float* __restrict__ dec,
    const float* __restrict__ Wa,  const float* __restrict__ Ua,
    float* __restrict__ EgT, float* __restrict__ FgT) {
  __shared__ float Mu[64 * 128];     // 32 KB: k-chunk of weight [k][h]
  __shared__ float rowsU[16 * 128];  // 8 KB: 16 input rows
  const float C2 = 2.8853900817779268f;  // 2*log2(e):  exp(2x) = exp2(C2*x)
  int tid = threadIdx.x;
  int r0 = blockIdx.x * 16;              // E/F boundary (16384) is block-aligned
  bool isE = (r0 < B * TE);
  const float* Mg = isE ? Wa : Ua;
  const float* in = isE ? enc : dec;
  int rbase = isE ? r0 : (r0 - B * TE);
  ((float4*)rowsU)[tid]       = ((const float4*)(in + (size_t)rbase * H))[tid];
  ((float4*)rowsU)[tid + 256] = ((const float4*)(in + (size_t)rbase * H))[tid + 256];
  int h = tid & 127, rl = tid >> 7;      // thread owns rows r = rl*8 + p (8 consecutive)
  float acc[8];
  #pragma unroll
  for (int p = 0; p < 8; ++p) acc[p] = 0.f;
  for (int kc = 0; kc < 128; kc += 64) {
    __syncthreads();                     // also covers rowsU visibility on kc==0
    #pragma unroll
    for (int i = 0; i < 8; ++i) {        // 64x128 floats = 2048 float4
      int f = tid + i * 256;
      ((float4*)Mu)[f] = ((const float4*)(Mg + (size_t)kc * H))[f];
    }
    __syncthreads();
    #pragma unroll
    for (int p = 0; p < 8; ++p) {
      int r = rl * 8 + p;
      float a = 0.f;
      #pragma unroll 8
      for (int k = 0; k < 64; ++k)
        a += rowsU[r * 128 + kc + k] * Mu[k * 128 + h];
      acc[p] += a;
    }
  }
  float4 lo, hi;
  lo.x = __builtin_amdgcn_exp2f(acc[0] * C2);
  lo.y = __builtin_amdgcn_exp2f(acc[1] * C2);
  lo.z = __builtin_amdgcn_exp2f(acc[2] * C2);
  lo.w = __builtin_amdgcn_exp2f(acc[3] * C2);
  hi.x = __builtin_amdgcn_exp2f(acc[4] * C2);
  hi.y = __builtin_amdgcn_exp2f(acc[5] * C2);
  hi.z = __builtin_amdgcn_exp2f(acc[6] * C2);
  hi.w = __builtin_amdgcn_exp2f(acc[7] * C2);
  if (isE) {                             // EgT[b][k=h][t]: 8 consecutive t per thread
    int b_e = rbase >> 11, t_in = (rbase & 2047) + rl * 8;
    float* dst = EgT + ((size_t)(b_e * H + h)) * TE + t_in;
    *(float4*)dst = lo; *(float4*)(dst + 4) = hi;
  } else {                               // FgT[b][k=h][j]: 8 consecutive j per thread
    int b_f = rbase >> 8, j_in = (rbase & 255) + rl * 8;
    float* dst = FgT + ((size_t)(b_f * H + h)) * TD + j_in;
    *(float4*)dst = lo; *(float4*)(dst + 4) = hi;
  }
}

// ---------- kernel 2: scores[b,j,t] = V1 - 2*sum_k v_k / (E[t,k]*F[j,k] + 1) ----------
// Zero LDS, zero barriers: lane = t (coalesced E^T b32), F/v wave-uniform -> scalar K$ loads.
__global__ __launch_bounds__(256) void scores_kernel(
    const float* __restrict__ EgT, const float* __restrict__ FgT,
    const float* __restrict__ Va, float* __restrict__ scores) {
  int tid = threadIdx.x;
  int tc = blockIdx.x, jt = blockIdx.y, b = blockIdx.z;
  int j0 = jt * 16;
  int w = tid >> 6, lane = tid & 63;
  int t = tc * 256 + w * 64 + lane;
  float s[16];
  #pragma unroll
  for (int j = 0; j < 16; ++j) s[j] = 0.f;
  float V1 = 0.f;
  const float* Ep = EgT + (size_t)b * H * TE + t;
  int fbase = b * H * TD + j0;
  #pragma unroll 2
  for (int k = 0; k < 128; ++k) {
    float Ek = Ep[(size_t)k * TE];                     // vector b32, coalesced in t
    int off = __builtin_amdgcn_readfirstlane(fbase + k * TD);
    const float* fp = FgT + off;                        // wave-uniform -> s_load
    float vk = Va[__builtin_amdgcn_readfirstlane(k)];   // wave-uniform -> s_load
    V1 += vk;
    #pragma unroll
    for (int j = 0; j < 16; ++j)
      s[j] += vk * __builtin_amdgcn_rcpf(fmaf(Ek, fp[j], 1.0f));
  }
  float* srow = scores + ((size_t)(b * TD + j0)) * TE + t;
  #pragma unroll
  for (int j = 0; j < 16; ++j)
    srow[(size_t)j * TE] = V1 - 2.0f * s[j];
}

// ---------- kernel 3: softmax over t -> e into d_out; also zeros this row's c slice ----------
__global__ __launch_bounds__(256) void softmax_kernel(
    const float* __restrict__ scores, float* __restrict__ eout,
    float4* __restrict__ c4) {
  __shared__ float red[4];
  int r = blockIdx.x, tid = threadIdx.x;
  if (tid < 32) c4[r * 32 + tid] = float4{0.f, 0.f, 0.f, 0.f};  // zero c for context's atomics
  const float* row = scores + (size_t)r * TE;
  float4 a = ((const float4*)row)[tid];
  float4 c = ((const float4*)row)[tid + 256];
  float m = fmaxf(fmaxf(fmaxf(a.x, a.y), fmaxf(a.z, a.w)),
                  fmaxf(fmaxf(c.x, c.y), fmaxf(c.z, c.w)));
  #pragma unroll
  for (int off = 32; off > 0; off >>= 1) m = fmaxf(m, __shfl_xor(m, off));
  int w = tid >> 6;
  if ((tid & 63) == 0) red[w] = m;
  __syncthreads();
  m = fmaxf(fmaxf(red[0], red[1]), fmaxf(red[2], red[3]));
  const float L2E = 1.4426950408889634f;
  a.x = __builtin_amdgcn_exp2f((a.x - m) * L2E);
  a.y = __builtin_amdgcn_exp2f((a.y - m) * L2E);
  a.z = __builtin_amdgcn_exp2f((a.z - m) * L2E);
  a.w = __builtin_amdgcn_exp2f((a.w - m) * L2E);
  c.x = __builtin_amdgcn_exp2f((c.x - m) * L2E);
  c.y = __builtin_amdgcn_exp2f((c.y - m) * L2E);
  c.z = __builtin_amdgcn_exp2f((c.z - m) * L2E);
  c.w = __builtin_amdgcn_exp2f((c.w - m) * L2E);
  float s = a.x + a.y + a.z + a.w + c.x + c.y + c.z + c.w;
  #pragma unroll
  for (int off = 32; off > 0; off >>= 1) s += __shfl_xor(s, off);
  __syncthreads();                 // red[] reuse
  if ((tid & 63) == 0) red[w] = s;
  __syncthreads();
  s = red[0] + red[1] + red[2] + red[3];
  float inv = 1.0f / s;            // precise div, once per thread
  a.x *= inv; a.y *= inv; a.z *= inv; a.w *= inv;
  c.x *= inv; c.y *= inv; c.z *= inv; c.w *= inv;
  float* orow = eout + (size_t)r * TE;
  ((float4*)orow)[tid] = a;
  ((float4*)orow)[tid + 256] = c;
}

// ---------- kernel 4: c[b,j,:] += sum_{t in 64-chunk} e[b,j,t]*enc[b,t,:] (atomic combine) ----------
// 512 thr, thread = 8j x 4h; P reads 2-addr broadcast (free), Et reads 4-way; 1 barrier/block.
__global__ __launch_bounds__(512) void context_kernel(
    const float* __restrict__ enc, const float* __restrict__ e,
    float* __restrict__ cout) {
  __shared__ float Et[64 * 128];   // 32 KB enc tile [t][h]
  __shared__ float P[128 * 64];    // 32 KB e tile [j][t]
  int tid = threadIdx.x;
  int jt = blockIdx.x, tch = blockIdx.y, b = blockIdx.z;
  int j0 = jt * 128, t0 = tch * 64;
  // stage enc tile: 2048 float4
  const float4* eg = (const float4*)(enc + ((size_t)b * TE + t0) * H);
  #pragma unroll
  for (int i = 0; i < 4; ++i) {
    int f = tid + i * 512;
    int tr = f >> 5, kc = (f & 31) * 4;
    *(float4*)&Et[tr * 128 + kc] = eg[f];
  }
  // stage e tile: thread reads 16 consecutive t of one j
  {
    int rd_j = tid >> 2, rd_t = (tid & 3) * 16;
    const float* ej = e + (size_t)(b * TD + j0 + rd_j) * TE + t0 + rd_t;
    #pragma unroll
    for (int s4 = 0; s4 < 4; ++s4)
      *(float4*)&P[rd_j * 64 + rd_t + s4 * 4] = *(const float4*)(ej + s4 * 4);
  }
  __syncthreads();
  int hg = tid & 31, jg = tid >> 5;     // h = hg*4; j = jg*8 + p
  float4 acc[8];
  #pragma unroll
  for (int p = 0; p < 8; ++p) acc[p] = float4{0.f, 0.f, 0.f, 0.f};
  #pragma unroll 2
  for (int tl4 = 0; tl4 < 64; tl4 += 4) {
    float4 pj[8];
    #pragma unroll
    for (int p = 0; p < 8; ++p)
      pj[p] = *(const float4*)&P[(jg * 8 + p) * 64 + tl4];   // 2-addr broadcast
    #pragma unroll
    for (int i = 0; i < 4; ++i) {
      float4 ev = *(const float4*)&Et[(tl4 + i) * 128 + hg * 4];
      float pv;
      #pragma unroll
      for (int p = 0; p < 8; ++p) {
        pv = (i == 0) ? pj[p].x : (i == 1) ? pj[p].y : (i == 2) ? pj[p].z : pj[p].w;
        acc[p].x += pv * ev.x; acc[p].y += pv * ev.y;
        acc[p].z += pv * ev.z; acc[p].w += pv * ev.w;
      }
    }
  }
  #pragma unroll
  for (int p = 0; p < 8; ++p) {
    float* cp = cout + (size_t)(b * TD + j0 + jg * 8 + p) * H + hg * 4;
    atomicAdd(cp + 0, acc[p].x); atomicAdd(cp + 1, acc[p].y);
    atomicAdd(cp + 2, acc[p].z); atomicAdd(cp + 3, acc[p].w);
  }
}

extern "C" void kernel_launch(void* const* d_in, const int* in_sizes, int n_in,
                              void* d_out, int out_size, void* d_ws, size_t ws_size,
                              hipStream_t stream) {
  (void)in_sizes; (void)n_in; (void)out_size; (void)ws_size;
  const float* enc = (const float*)d_in[0];
  const float* dec = (const float*)d_in[1];
  const float* Wa  = (const float*)d_in[2];
  const float* Ua  = (const float*)d_in[3];
  const float* Va  = (const float*)d_in[4];

  float* ws     = (float*)d_ws;
  float* EgT    = ws;                                    //  2,097,152 f32 (8 MB)  exp(2 enc@W)^T [b][k][t]
  float* FgT    = EgT + (size_t)B * TE * H;              //    262,144 f32 (1 MB)  exp(2 dec@U)^T [b][k][j]
  float* scores = FgT + (size_t)B * TD * H;              //  4,194,304 f32 (16 MB)
  float* outc = (float*)d_out;                           // c [B,TD,H] fp32
  float* oute = outc + (size_t)B * TD * H;               // e [B,TD,TE] fp32

  proj_kernel<<<dim3((B * TE + B * TD) / 16), 256, 0, stream>>>(enc, dec, Wa, Ua, EgT, FgT);
  scores_kernel<<<dim3(8, 16, 8), 256, 0, stream>>>(EgT, FgT, Va, scores);
  softmax_kernel<<<dim3(B * TD), 256, 0, stream>>>(scores, oute, (float4*)outc);
  context_kernel<<<dim3(2, 32, 8), 512, 0, stream>>>(enc, oute, outc);
}

// Round 7
// 227.013 us; speedup vs baseline: 1.2694x; 1.2694x over previous
//
#include <hip/hip_runtime.h>
#include <stdint.h>

#define B  8
#define TE 2048
#define TD 256
#define H  128

// ---------- kernel 1: EgT[b][k][t] = exp(2*(enc@W_a))^T ; Fg[b][j][k] = exp(2*(dec@U_a)) ----------
__global__ __launch_bounds__(256) void proj_kernel(
    const float* __restrict__ enc, const float* __restrict__ dec,
    const float* __restrict__ Wa,  const float* __restrict__ Ua,
    float* __restrict__ EgT, float* __restrict__ Fg) {
  __shared__ float Mu[64 * 128];     // 32 KB: k-chunk of weight [k][h]
  __shared__ float rowsU[16 * 128];  // 8 KB: 16 input rows
  const float C2 = 2.8853900817779268f;  // 2*log2(e):  exp(2x) = exp2(C2*x)
  int tid = threadIdx.x;
  int r0 = blockIdx.x * 16;              // E/F boundary (16384) is block-aligned
  bool isE = (r0 < B * TE);
  const float* Mg = isE ? Wa : Ua;
  const float* in = isE ? enc : dec;
  int rbase = isE ? r0 : (r0 - B * TE);
  ((float4*)rowsU)[tid]       = ((const float4*)(in + (size_t)rbase * H))[tid];
  ((float4*)rowsU)[tid + 256] = ((const float4*)(in + (size_t)rbase * H))[tid + 256];
  int h = tid & 127, rl = tid >> 7;      // thread owns rows r = rl*8 + p (8 consecutive)
  float acc[8];
  #pragma unroll
  for (int p = 0; p < 8; ++p) acc[p] = 0.f;
  for (int kc = 0; kc < 128; kc += 64) {
    __syncthreads();                     // also covers rowsU visibility on kc==0
    #pragma unroll
    for (int i = 0; i < 8; ++i) {        // 64x128 floats = 2048 float4
      int f = tid + i * 256;
      ((float4*)Mu)[f] = ((const float4*)(Mg + (size_t)kc * H))[f];
    }
    __syncthreads();
    #pragma unroll
    for (int p = 0; p < 8; ++p) {
      int r = rl * 8 + p;
      float a = 0.f;
      #pragma unroll 8
      for (int k = 0; k < 64; ++k)
        a += rowsU[r * 128 + kc + k] * Mu[k * 128 + h];
      acc[p] += a;
    }
  }
  float ex[8];
  #pragma unroll
  for (int p = 0; p < 8; ++p) ex[p] = __builtin_amdgcn_exp2f(acc[p] * C2);
  if (isE) {                             // EgT[b][k=h][t]: 8 consecutive t per thread
    int b_e = rbase >> 11, t_in = (rbase & 2047) + rl * 8;
    float* dst = EgT + ((size_t)(b_e * H + h)) * TE + t_in;
    *(float4*)dst = float4{ex[0], ex[1], ex[2], ex[3]};
    *(float4*)(dst + 4) = float4{ex[4], ex[5], ex[6], ex[7]};
  } else {                               // Fg[b][j][k]: row-major, coalesced over h(=k)
    #pragma unroll
    for (int p = 0; p < 8; ++p)
      Fg[(size_t)(rbase + rl * 8 + p) * H + h] = ex[p];
  }
}

// ---------- kernel 2: scores[b,j,t] = V1 - 2*sum_k v_k / (E[t,k]*F[j,k] + 1) ----------
// Zero LDS, zero barriers. E coalesced from EgT[k][t]; F/v in registers, k-chunked (16 k).
// Thread: 2 j (w, w+4) x 4 t-slots; wave = 64 consecutive t.
__global__ __launch_bounds__(256) void scores_kernel(
    const float* __restrict__ EgT, const float* __restrict__ Fg,
    const float* __restrict__ Va, float* __restrict__ scores) {
  int tid = threadIdx.x;
  int tc = blockIdx.x, jt = blockIdx.y, b = blockIdx.z;
  int lane = tid & 63, w = tid >> 6;
  int j1 = jt * 8 + w, j2 = j1 + 4;
  const float* Ep = EgT + (size_t)b * H * TE + tc * 256 + lane;
  const float4* fap = (const float4*)(Fg + (size_t)(b * TD + j1) * H);
  const float4* fbp = (const float4*)(Fg + (size_t)(b * TD + j2) * H);
  const float4* vp  = (const float4*)Va;
  float s1[4] = {0.f, 0.f, 0.f, 0.f}, s2[4] = {0.f, 0.f, 0.f, 0.f};
  float V1 = 0.f;
  for (int kc = 0; kc < 8; ++kc) {       // k-chunks of 16
    float4 fa[4], fb[4], v[4];
    #pragma unroll
    for (int q = 0; q < 4; ++q) {
      fa[q] = fap[kc * 4 + q]; fb[q] = fbp[kc * 4 + q]; v[q] = vp[kc * 4 + q];
    }
    #pragma unroll
    for (int q = 0; q < 4; ++q) V1 += v[q].x + v[q].y + v[q].z + v[q].w;
    #pragma unroll
    for (int s = 0; s < 4; ++s) {        // 4 t-slots, 64 apart
      const float* ep = Ep + (size_t)(kc * 16) * TE + s * 64;
      #pragma unroll
      for (int q = 0; q < 4; ++q) {
        float e0 = ep[(size_t)(q * 4 + 0) * TE];
        float e1 = ep[(size_t)(q * 4 + 1) * TE];
        float e2 = ep[(size_t)(q * 4 + 2) * TE];
        float e3 = ep[(size_t)(q * 4 + 3) * TE];
        s1[s] += v[q].x * __builtin_amdgcn_rcpf(fmaf(e0, fa[q].x, 1.0f));
        s1[s] += v[q].y * __builtin_amdgcn_rcpf(fmaf(e1, fa[q].y, 1.0f));
        s1[s] += v[q].z * __builtin_amdgcn_rcpf(fmaf(e2, fa[q].z, 1.0f));
        s1[s] += v[q].w * __builtin_amdgcn_rcpf(fmaf(e3, fa[q].w, 1.0f));
        s2[s] += v[q].x * __builtin_amdgcn_rcpf(fmaf(e0, fb[q].x, 1.0f));
        s2[s] += v[q].y * __builtin_amdgcn_rcpf(fmaf(e1, fb[q].y, 1.0f));
        s2[s] += v[q].z * __builtin_amdgcn_rcpf(fmaf(e2, fb[q].z, 1.0f));
        s2[s] += v[q].w * __builtin_amdgcn_rcpf(fmaf(e3, fb[q].w, 1.0f));
      }
    }
  }
  float* r1 = scores + (size_t)(b * TD + j1) * TE + tc * 256 + lane;
  float* r2 = scores + (size_t)(b * TD + j2) * TE + tc * 256 + lane;
  #pragma unroll
  for (int s = 0; s < 4; ++s) {
    r1[s * 64] = V1 - 2.0f * s1[s];
    r2[s * 64] = V1 - 2.0f * s2[s];
  }
}

// ---------- kernel 3: softmax over t -> e into d_out ----------
__global__ __launch_bounds__(256) void softmax_kernel(
    const float* __restrict__ scores, float* __restrict__ eout) {
  __shared__ float red[4];
  int r = blockIdx.x, tid = threadIdx.x;
  const float* row = scores + (size_t)r * TE;
  float4 a = ((const float4*)row)[tid];
  float4 c = ((const float4*)row)[tid + 256];
  float m = fmaxf(fmaxf(fmaxf(a.x, a.y), fmaxf(a.z, a.w)),
                  fmaxf(fmaxf(c.x, c.y), fmaxf(c.z, c.w)));
  #pragma unroll
  for (int off = 32; off > 0; off >>= 1) m = fmaxf(m, __shfl_xor(m, off));
  int w = tid >> 6;
  if ((tid & 63) == 0) red[w] = m;
  __syncthreads();
  m = fmaxf(fmaxf(red[0], red[1]), fmaxf(red[2], red[3]));
  const float L2E = 1.4426950408889634f;
  a.x = __builtin_amdgcn_exp2f((a.x - m) * L2E);
  a.y = __builtin_amdgcn_exp2f((a.y - m) * L2E);
  a.z = __builtin_amdgcn_exp2f((a.z - m) * L2E);
  a.w = __builtin_amdgcn_exp2f((a.w - m) * L2E);
  c.x = __builtin_amdgcn_exp2f((c.x - m) * L2E);
  c.y = __builtin_amdgcn_exp2f((c.y - m) * L2E);
  c.z = __builtin_amdgcn_exp2f((c.z - m) * L2E);
  c.w = __builtin_amdgcn_exp2f((c.w - m) * L2E);
  float s = a.x + a.y + a.z + a.w + c.x + c.y + c.z + c.w;
  #pragma unroll
  for (int off = 32; off > 0; off >>= 1) s += __shfl_xor(s, off);
  __syncthreads();                 // red[] reuse
  if ((tid & 63) == 0) red[w] = s;
  __syncthreads();
  s = red[0] + red[1] + red[2] + red[3];
  float inv = 1.0f / s;            // precise div, once per thread
  a.x *= inv; a.y *= inv; a.z *= inv; a.w *= inv;
  c.x *= inv; c.y *= inv; c.z *= inv; c.w *= inv;
  float* orow = eout + (size_t)r * TE;
  ((float4*)orow)[tid] = a;
  ((float4*)orow)[tid + 256] = c;
}

// ---------- kernel 4: partial c over a 128-t chunk; no LDS, no barriers, no atomics ----------
// Thread: 4 j x 8 h register tile; e rows block-exclusive (streamed), enc rows L1-merged.
__global__ __launch_bounds__(512) void context_kernel(
    const float* __restrict__ enc, const float* __restrict__ e,
    float* __restrict__ part) {
  int tid = threadIdx.x;
  int jt = blockIdx.x, tch = blockIdx.y, b = blockIdx.z;
  int hg = tid & 15, jg = tid >> 4;     // h0 = hg*8; j = jt*128 + jg*4 + p
  int h0 = hg * 8;
  int j = jt * 128 + jg * 4;
  int t0 = tch * 128;
  const float* e0p  = e + (size_t)(b * TD + j) * TE + t0;
  const float* encp = enc + ((size_t)b * TE + t0) * H + h0;
  float4 acc[4][2];
  #pragma unroll
  for (int p = 0; p < 4; ++p) {
    acc[p][0] = float4{0.f, 0.f, 0.f, 0.f};
    acc[p][1] = float4{0.f, 0.f, 0.f, 0.f};
  }
  #pragma unroll 2
  for (int t4 = 0; t4 < 128; t4 += 4) {
    float4 pj[4];
    #pragma unroll
    for (int p = 0; p < 4; ++p)
      pj[p] = *(const float4*)(e0p + (size_t)p * TE + t4);
    #pragma unroll
    for (int i = 0; i < 4; ++i) {
      const float* er = encp + (size_t)(t4 + i) * H;
      float4 ev0 = *(const float4*)er;
      float4 ev1 = *(const float4*)(er + 4);
      #pragma unroll
      for (int p = 0; p < 4; ++p) {
        float pv = (i == 0) ? pj[p].x : (i == 1) ? pj[p].y : (i == 2) ? pj[p].z : pj[p].w;
        acc[p][0].x += pv * ev0.x; acc[p][0].y += pv * ev0.y;
        acc[p][0].z += pv * ev0.z; acc[p][0].w += pv * ev0.w;
        acc[p][1].x += pv * ev1.x; acc[p][1].y += pv * ev1.y;
        acc[p][1].z += pv * ev1.z; acc[p][1].w += pv * ev1.w;
      }
    }
  }
  #pragma unroll
  for (int p = 0; p < 4; ++p) {
    float* dst = part + (size_t)tch * (B * TD * H) + (size_t)(b * TD + j + p) * H + h0;
    *(float4*)dst = acc[p][0];
    *(float4*)(dst + 4) = acc[p][1];
  }
}

// ---------- kernel 5: c = sum of 16 partials ----------
__global__ __launch_bounds__(256) void reduce_kernel(
    const float4* __restrict__ part, float4* __restrict__ outc) {
  int i = blockIdx.x * 256 + threadIdx.x;      // 65536 float4 outputs
  float4 a = part[i];
  #pragma unroll
  for (int q = 1; q < 16; ++q) {
    float4 p = part[(size_t)q * 65536 + i];
    a.x += p.x; a.y += p.y; a.z += p.z; a.w += p.w;
  }
  outc[i] = a;
}

extern "C" void kernel_launch(void* const* d_in, const int* in_sizes, int n_in,
                              void* d_out, int out_size, void* d_ws, size_t ws_size,
                              hipStream_t stream) {
  (void)in_sizes; (void)n_in; (void)out_size; (void)ws_size;
  const float* enc = (const float*)d_in[0];
  const float* dec = (const float*)d_in[1];
  const float* Wa  = (const float*)d_in[2];
  const float* Ua  = (const float*)d_in[3];
  const float* Va  = (const float*)d_in[4];

  float* ws     = (float*)d_ws;
  float* EgT    = ws;                                    //  2,097,152 f32 (8 MB)  exp(2 enc@W)^T [b][k][t]
  float* Fg     = EgT + (size_t)B * TE * H;              //    262,144 f32 (1 MB)  exp(2 dec@U)   [b][j][k]
  float* scores = Fg + (size_t)B * TD * H;               //  4,194,304 f32 (16 MB); reused as 16 c-partials
  float* outc = (float*)d_out;                           // c [B,TD,H] fp32
  float* oute = outc + (size_t)B * TD * H;               // e [B,TD,TE] fp32

  proj_kernel<<<dim3((B * TE + B * TD) / 16), 256, 0, stream>>>(enc, dec, Wa, Ua, EgT, Fg);
  scores_kernel<<<dim3(8, 32, 8), 256, 0, stream>>>(EgT, Fg, Va, scores);
  softmax_kernel<<<dim3(B * TD), 256, 0, stream>>>(scores, oute);
  context_kernel<<<dim3(2, 16, 8), 512, 0, stream>>>(enc, oute, scores);  // partials -> dead scores region
  reduce_kernel<<<dim3(256), 256, 0, stream>>>((const float4*)scores, (float4*)outc);
}

// Round 8
// 201.183 us; speedup vs baseline: 1.4324x; 1.1284x over previous
//
#include <hip/hip_runtime.h>
#include <stdint.h>

#define B  8
#define TE 2048
#define TD 256
#define H  128

// ---------- kernel 1: register-tiled GEMM, no LDS in main loop ----------
// E written t-tiled: EgT[b][tb][k][tl]  (tb = t>>6, tl = t&63); F row-major [b][j][k].
__global__ __launch_bounds__(256) void proj_kernel(
    const float* __restrict__ enc, const float* __restrict__ dec,
    const float* __restrict__ Wa,  const float* __restrict__ Ua,
    float* __restrict__ EgT, float* __restrict__ Fg) {
  __shared__ float Ls[32 * 132];         // 16.9 KB: E-epilogue transpose only
  const float C2 = 2.8853900817779268f;  // 2*log2(e):  exp(2x) = exp2(C2*x)
  int tid = threadIdx.x;
  int bid = blockIdx.x;
  bool isE = (bid < 512);
  int rbase = (isE ? bid : bid - 512) * 32;
  const float* in = isE ? enc : dec;
  const float* Mg = isE ? Wa : Ua;
  int hq = tid & 31, rq = tid >> 5;      // h0 = hq*4 (lanes cover 128 h), r0 = rq*4
  int h0 = hq * 4, r0 = rq * 4;
  const float* rowp = in + (size_t)(rbase + r0) * H;   // 4 rows, stride H
  const float* wp = Mg + h0;                           // weight col-block, stride H
  float4 a0{0,0,0,0}, a1{0,0,0,0}, a2{0,0,0,0}, a3{0,0,0,0};
  #pragma unroll 4
  for (int k = 0; k < 128; ++k) {
    float4 wv = *(const float4*)(wp + (size_t)k * H);  // coalesced b128
    float r0v = rowp[k];                               // 2-addr broadcast b32
    float r1v = rowp[k + H];
    float r2v = rowp[k + 2 * H];
    float r3v = rowp[k + 3 * H];
    a0.x += r0v * wv.x; a0.y += r0v * wv.y; a0.z += r0v * wv.z; a0.w += r0v * wv.w;
    a1.x += r1v * wv.x; a1.y += r1v * wv.y; a1.z += r1v * wv.z; a1.w += r1v * wv.w;
    a2.x += r2v * wv.x; a2.y += r2v * wv.y; a2.z += r2v * wv.z; a2.w += r2v * wv.w;
    a3.x += r3v * wv.x; a3.y += r3v * wv.y; a3.z += r3v * wv.z; a3.w += r3v * wv.w;
  }
  float4 e0, e1, e2, e3;
  e0.x = __builtin_amdgcn_exp2f(a0.x * C2); e0.y = __builtin_amdgcn_exp2f(a0.y * C2);
  e0.z = __builtin_amdgcn_exp2f(a0.z * C2); e0.w = __builtin_amdgcn_exp2f(a0.w * C2);
  e1.x = __builtin_amdgcn_exp2f(a1.x * C2); e1.y = __builtin_amdgcn_exp2f(a1.y * C2);
  e1.z = __builtin_amdgcn_exp2f(a1.z * C2); e1.w = __builtin_amdgcn_exp2f(a1.w * C2);
  e2.x = __builtin_amdgcn_exp2f(a2.x * C2); e2.y = __builtin_amdgcn_exp2f(a2.y * C2);
  e2.z = __builtin_amdgcn_exp2f(a2.z * C2); e2.w = __builtin_amdgcn_exp2f(a2.w * C2);
  e3.x = __builtin_amdgcn_exp2f(a3.x * C2); e3.y = __builtin_amdgcn_exp2f(a3.y * C2);
  e3.z = __builtin_amdgcn_exp2f(a3.z * C2); e3.w = __builtin_amdgcn_exp2f(a3.w * C2);
  if (isE) {
    // flip through LDS so global writes are consecutive-t coalesced
    *(float4*)&Ls[(r0 + 0) * 132 + h0] = e0;
    *(float4*)&Ls[(r0 + 1) * 132 + h0] = e1;
    *(float4*)&Ls[(r0 + 2) * 132 + h0] = e2;
    *(float4*)&Ls[(r0 + 3) * 132 + h0] = e3;
    __syncthreads();
    int b_e = rbase >> 11, t_in = rbase & 2047;
    int tb = t_in >> 6, toff = t_in & 63;
    float* dst = EgT + ((size_t)(b_e * 32 + tb) * 128) * 64 + toff;
    #pragma unroll
    for (int jj = 0; jj < 16; ++jj) {
      int idx = jj * 256 + tid;
      int r = idx & 31, k = idx >> 5;
      dst[(size_t)k * 64 + r] = Ls[r * 132 + k];
    }
  } else {
    int b_f = rbase >> 8, j_in = rbase & 255;
    float* dst = Fg + ((size_t)(b_f * TD + j_in + r0)) * H + h0;
    *(float4*)(dst + 0 * H) = e0;
    *(float4*)(dst + 1 * H) = e1;
    *(float4*)(dst + 2 * H) = e2;
    *(float4*)(dst + 3 * H) = e3;
  }
}

// ---------- kernel 2: scores[b,j,t] = V1 - 2*sum_k v_k / (E[t,k]*F[j,k] + 1) ----------
// Zero LDS/barriers. Wave w owns tb = tc*4+w (lane = tl); thread handles 8 j.
// All loads are base-bump + immediate-offset (k-stride 256 B in tiled E).
__global__ __launch_bounds__(256) void scores_kernel(
    const float* __restrict__ EgT, const float* __restrict__ Fg,
    const float* __restrict__ Va, float* __restrict__ scores) {
  int tid = threadIdx.x;
  int tc = blockIdx.x, jt = blockIdx.y, b = blockIdx.z;
  int lane = tid & 63, w = tid >> 6;
  int tb = tc * 4 + w;
  int j0 = jt * 8;
  const float* Ep = EgT + ((size_t)(b * 32 + tb) * 128) * 64 + lane;
  const float4* Fp = (const float4*)(Fg + (size_t)(b * TD + j0) * H);
  const float4* vp = (const float4*)Va;
  float s[8] = {0.f, 0.f, 0.f, 0.f, 0.f, 0.f, 0.f, 0.f};
  float V1 = 0.f;
  for (int kc = 0; kc < 16; ++kc) {      // 8 k per chunk
    const float* ep = Ep + kc * 512;     // 8 k x 64 tl
    float ek[8];
    #pragma unroll
    for (int q = 0; q < 8; ++q) ek[q] = ep[q * 64];   // imm offsets 0..1792 B
    float4 v0 = vp[kc * 2], v1 = vp[kc * 2 + 1];
    V1 += v0.x + v0.y + v0.z + v0.w + v1.x + v1.y + v1.z + v1.w;
    const float4* fp = Fp + kc * 2;
    #pragma unroll
    for (int j = 0; j < 8; ++j) {
      float4 f0 = fp[j * 32];            // imm offsets j*512 B
      float4 f1 = fp[j * 32 + 1];
      s[j] += v0.x * __builtin_amdgcn_rcpf(fmaf(ek[0], f0.x, 1.0f));
      s[j] += v0.y * __builtin_amdgcn_rcpf(fmaf(ek[1], f0.y, 1.0f));
      s[j] += v0.z * __builtin_amdgcn_rcpf(fmaf(ek[2], f0.z, 1.0f));
      s[j] += v0.w * __builtin_amdgcn_rcpf(fmaf(ek[3], f0.w, 1.0f));
      s[j] += v1.x * __builtin_amdgcn_rcpf(fmaf(ek[4], f1.x, 1.0f));
      s[j] += v1.y * __builtin_amdgcn_rcpf(fmaf(ek[5], f1.y, 1.0f));
      s[j] += v1.z * __builtin_amdgcn_rcpf(fmaf(ek[6], f1.z, 1.0f));
      s[j] += v1.w * __builtin_amdgcn_rcpf(fmaf(ek[7], f1.w, 1.0f));
    }
  }
  int t = tb * 64 + lane;
  float* srow = scores + (size_t)(b * TD + j0) * TE + t;
  #pragma unroll
  for (int j = 0; j < 8; ++j)
    srow[(size_t)j * TE] = V1 - 2.0f * s[j];
}

// ---------- kernel 3: softmax over t -> e into d_out ----------
__global__ __launch_bounds__(256) void softmax_kernel(
    const float* __restrict__ scores, float* __restrict__ eout) {
  __shared__ float red[4];
  int r = blockIdx.x, tid = threadIdx.x;
  const float* row = scores + (size_t)r * TE;
  float4 a = ((const float4*)row)[tid];
  float4 c = ((const float4*)row)[tid + 256];
  float m = fmaxf(fmaxf(fmaxf(a.x, a.y), fmaxf(a.z, a.w)),
                  fmaxf(fmaxf(c.x, c.y), fmaxf(c.z, c.w)));
  #pragma unroll
  for (int off = 32; off > 0; off >>= 1) m = fmaxf(m, __shfl_xor(m, off));
  int w = tid >> 6;
  if ((tid & 63) == 0) red[w] = m;
  __syncthreads();
  m = fmaxf(fmaxf(red[0], red[1]), fmaxf(red[2], red[3]));
  const float L2E = 1.4426950408889634f;
  a.x = __builtin_amdgcn_exp2f((a.x - m) * L2E);
  a.y = __builtin_amdgcn_exp2f((a.y - m) * L2E);
  a.z = __builtin_amdgcn_exp2f((a.z - m) * L2E);
  a.w = __builtin_amdgcn_exp2f((a.w - m) * L2E);
  c.x = __builtin_amdgcn_exp2f((c.x - m) * L2E);
  c.y = __builtin_amdgcn_exp2f((c.y - m) * L2E);
  c.z = __builtin_amdgcn_exp2f((c.z - m) * L2E);
  c.w = __builtin_amdgcn_exp2f((c.w - m) * L2E);
  float s = a.x + a.y + a.z + a.w + c.x + c.y + c.z + c.w;
  #pragma unroll
  for (int off = 32; off > 0; off >>= 1) s += __shfl_xor(s, off);
  __syncthreads();                 // red[] reuse
  if ((tid & 63) == 0) red[w] = s;
  __syncthreads();
  s = red[0] + red[1] + red[2] + red[3];
  float inv = 1.0f / s;            // precise div, once per thread
  a.x *= inv; a.y *= inv; a.z *= inv; a.w *= inv;
  c.x *= inv; c.y *= inv; c.z *= inv; c.w *= inv;
  float* orow = eout + (size_t)r * TE;
  ((float4*)orow)[tid] = a;
  ((float4*)orow)[tid + 256] = c;
}

// ---------- kernel 4: partial c over a 128-t chunk; no LDS, no barriers, no atomics ----------
__global__ __launch_bounds__(512) void context_kernel(
    const float* __restrict__ enc, const float* __restrict__ e,
    float* __restrict__ part) {
  int tid = threadIdx.x;
  int jt = blockIdx.x, tch = blockIdx.y, b = blockIdx.z;
  int hg = tid & 15, jg = tid >> 4;     // h0 = hg*8; j = jt*128 + jg*4 + p
  int h0 = hg * 8;
  int j = jt * 128 + jg * 4;
  int t0 = tch * 128;
  const float* e0p  = e + (size_t)(b * TD + j) * TE + t0;
  const float* encp = enc + ((size_t)b * TE + t0) * H + h0;
  float4 acc[4][2];
  #pragma unroll
  for (int p = 0; p < 4; ++p) {
    acc[p][0] = float4{0.f, 0.f, 0.f, 0.f};
    acc[p][1] = float4{0.f, 0.f, 0.f, 0.f};
  }
  #pragma unroll 2
  for (int t4 = 0; t4 < 128; t4 += 4) {
    float4 pj[4];
    #pragma unroll
    for (int p = 0; p < 4; ++p)
      pj[p] = *(const float4*)(e0p + (size_t)p * TE + t4);
    #pragma unroll
    for (int i = 0; i < 4; ++i) {
      const float* er = encp + (size_t)(t4 + i) * H;
      float4 ev0 = *(const float4*)er;
      float4 ev1 = *(const float4*)(er + 4);
      #pragma unroll
      for (int p = 0; p < 4; ++p) {
        float pv = (i == 0) ? pj[p].x : (i == 1) ? pj[p].y : (i == 2) ? pj[p].z : pj[p].w;
        acc[p][0].x += pv * ev0.x; acc[p][0].y += pv * ev0.y;
        acc[p][0].z += pv * ev0.z; acc[p][0].w += pv * ev0.w;
        acc[p][1].x += pv * ev1.x; acc[p][1].y += pv * ev1.y;
        acc[p][1].z += pv * ev1.z; acc[p][1].w += pv * ev1.w;
      }
    }
  }
  #pragma unroll
  for (int p = 0; p < 4; ++p) {
    float* dst = part + (size_t)tch * (B * TD * H) + (size_t)(b * TD + j + p) * H + h0;
    *(float4*)dst = acc[p][0];
    *(float4*)(dst + 4) = acc[p][1];
  }
}

// ---------- kernel 5: c = sum of 16 partials ----------
__global__ __launch_bounds__(256) void reduce_kernel(
    const float4* __restrict__ part, float4* __restrict__ outc) {
  int i = blockIdx.x * 256 + threadIdx.x;      // 65536 float4 outputs
  float4 a = part[i];
  #pragma unroll
  for (int q = 1; q < 16; ++q) {
    float4 p = part[(size_t)q * 65536 + i];
    a.x += p.x; a.y += p.y; a.z += p.z; a.w += p.w;
  }
  outc[i] = a;
}

extern "C" void kernel_launch(void* const* d_in, const int* in_sizes, int n_in,
                              void* d_out, int out_size, void* d_ws, size_t ws_size,
                              hipStream_t stream) {
  (void)in_sizes; (void)n_in; (void)out_size; (void)ws_size;
  const float* enc = (const float*)d_in[0];
  const float* dec = (const float*)d_in[1];
  const float* Wa  = (const float*)d_in[2];
  const float* Ua  = (const float*)d_in[3];
  const float* Va  = (const float*)d_in[4];

  float* ws     = (float*)d_ws;
  float* EgT    = ws;                                    //  2,097,152 f32 (8 MB)  E tiled [b][tb][k][tl]
  float* Fg     = EgT + (size_t)B * TE * H;              //    262,144 f32 (1 MB)  F [b][j][k]
  float* scores = Fg + (size_t)B * TD * H;               //  4,194,304 f32 (16 MB); reused as 16 c-partials
  float* outc = (float*)d_out;                           // c [B,TD,H] fp32
  float* oute = outc + (size_t)B * TD * H;               // e [B,TD,TE] fp32

  proj_kernel<<<dim3(576), 256, 0, stream>>>(enc, dec, Wa, Ua, EgT, Fg);
  scores_kernel<<<dim3(8, 32, 8), 256, 0, stream>>>(EgT, Fg, Va, scores);
  softmax_kernel<<<dim3(B * TD), 256, 0, stream>>>(scores, oute);
  context_kernel<<<dim3(2, 16, 8), 512, 0, stream>>>(enc, oute, scores);  // partials -> dead scores region
  reduce_kernel<<<dim3(256), 256, 0, stream>>>((const float4*)scores, (float4*)outc);
}

// Round 9
// 175.416 us; speedup vs baseline: 1.6428x; 1.1469x over previous
//
#include <hip/hip_runtime.h>
#include <stdint.h>

#define B  8
#define TE 2048
#define TD 256
#define H  128

// ---------- kernel 1: register-tiled GEMM, no LDS in main loop ----------
// E written t-tiled: EgT[b][tb][k][tl]  (tb = t>>6, tl = t&63); F row-major [b][j][k].
__global__ __launch_bounds__(256) void proj_kernel(
    const float* __restrict__ enc, const float* __restrict__ dec,
    const float* __restrict__ Wa,  const float* __restrict__ Ua,
    float* __restrict__ EgT, float* __restrict__ Fg) {
  __shared__ float Ls[32 * 132];         // 16.9 KB: E-epilogue transpose only
  const float C2 = 2.8853900817779268f;  // 2*log2(e):  exp(2x) = exp2(C2*x)
  int tid = threadIdx.x;
  int bid = blockIdx.x;
  bool isE = (bid < 512);
  int rbase = (isE ? bid : bid - 512) * 32;
  const float* in = isE ? enc : dec;
  const float* Mg = isE ? Wa : Ua;
  int hq = tid & 31, rq = tid >> 5;      // h0 = hq*4 (lanes cover 128 h), r0 = rq*4
  int h0 = hq * 4, r0 = rq * 4;
  const float* rowp = in + (size_t)(rbase + r0) * H;   // 4 rows, stride H
  const float* wp = Mg + h0;                           // weight col-block, stride H
  float4 a0{0,0,0,0}, a1{0,0,0,0}, a2{0,0,0,0}, a3{0,0,0,0};
  #pragma unroll 4
  for (int k = 0; k < 128; ++k) {
    float4 wv = *(const float4*)(wp + (size_t)k * H);  // coalesced b128
    float r0v = rowp[k];                               // 2-addr broadcast b32
    float r1v = rowp[k + H];
    float r2v = rowp[k + 2 * H];
    float r3v = rowp[k + 3 * H];
    a0.x += r0v * wv.x; a0.y += r0v * wv.y; a0.z += r0v * wv.z; a0.w += r0v * wv.w;
    a1.x += r1v * wv.x; a1.y += r1v * wv.y; a1.z += r1v * wv.z; a1.w += r1v * wv.w;
    a2.x += r2v * wv.x; a2.y += r2v * wv.y; a2.z += r2v * wv.z; a2.w += r2v * wv.w;
    a3.x += r3v * wv.x; a3.y += r3v * wv.y; a3.z += r3v * wv.z; a3.w += r3v * wv.w;
  }
  float4 e0, e1, e2, e3;
  e0.x = __builtin_amdgcn_exp2f(a0.x * C2); e0.y = __builtin_amdgcn_exp2f(a0.y * C2);
  e0.z = __builtin_amdgcn_exp2f(a0.z * C2); e0.w = __builtin_amdgcn_exp2f(a0.w * C2);
  e1.x = __builtin_amdgcn_exp2f(a1.x * C2); e1.y = __builtin_amdgcn_exp2f(a1.y * C2);
  e1.z = __builtin_amdgcn_exp2f(a1.z * C2); e1.w = __builtin_amdgcn_exp2f(a1.w * C2);
  e2.x = __builtin_amdgcn_exp2f(a2.x * C2); e2.y = __builtin_amdgcn_exp2f(a2.y * C2);
  e2.z = __builtin_amdgcn_exp2f(a2.z * C2); e2.w = __builtin_amdgcn_exp2f(a2.w * C2);
  e3.x = __builtin_amdgcn_exp2f(a3.x * C2); e3.y = __builtin_amdgcn_exp2f(a3.y * C2);
  e3.z = __builtin_amdgcn_exp2f(a3.z * C2); e3.w = __builtin_amdgcn_exp2f(a3.w * C2);
  if (isE) {
    // flip through LDS so global writes are consecutive-t coalesced
    *(float4*)&Ls[(r0 + 0) * 132 + h0] = e0;
    *(float4*)&Ls[(r0 + 1) * 132 + h0] = e1;
    *(float4*)&Ls[(r0 + 2) * 132 + h0] = e2;
    *(float4*)&Ls[(r0 + 3) * 132 + h0] = e3;
    __syncthreads();
    int b_e = rbase >> 11, t_in = rbase & 2047;
    int tb = t_in >> 6, toff = t_in & 63;
    float* dst = EgT + ((size_t)(b_e * 32 + tb) * 128) * 64 + toff;
    #pragma unroll
    for (int jj = 0; jj < 16; ++jj) {
      int idx = jj * 256 + tid;
      int r = idx & 31, k = idx >> 5;
      dst[(size_t)k * 64 + r] = Ls[r * 132 + k];
    }
  } else {
    int b_f = rbase >> 8, j_in = rbase & 255;
    float* dst = Fg + ((size_t)(b_f * TD + j_in + r0)) * H + h0;
    *(float4*)(dst + 0 * H) = e0;
    *(float4*)(dst + 1 * H) = e1;
    *(float4*)(dst + 2 * H) = e2;
    *(float4*)(dst + 3 * H) = e3;
  }
}

// ---------- kernel 2: fused scores -> softmax -> context ----------
// Block owns (b, 4 j-rows, all 2048 t). 512 thr = 8 waves, 32 KB LDS, grid (64,8)=512 blocks.
__global__ __launch_bounds__(512) void fused_kernel(
    const float* __restrict__ EgT, const float* __restrict__ Fg,
    const float* __restrict__ Va,  const float* __restrict__ enc,
    float* __restrict__ oute, float* __restrict__ outc) {
  __shared__ float S[4 * 2048];    // 32 KB: raw scores [j][t] -> e [t][4j] -> c-partials [slice][j][h]
  __shared__ float red[16];
  int tid = threadIdx.x;
  int jt = blockIdx.x, b = blockIdx.y;
  int j0 = jt * 4;
  int lane = tid & 63, w = tid >> 6;
  const float4* vp = (const float4*)Va;
  float V1 = 0.f;                  // sum_k v_k (L1-hot broadcast loads)
  #pragma unroll
  for (int q = 0; q < 32; ++q) { float4 v = vp[q]; V1 += v.x + v.y + v.z + v.w; }

  // ---- phase 1: scores[j][t] = V1 - 2*sum_k v_k/(E[t,k]*F[j,k]+1) into LDS ----
  const float4* Fp = (const float4*)(Fg + (size_t)(b * TD + j0) * H);
  for (int it = 0; it < 4; ++it) {
    int tb = w + 8 * it;                       // 8 waves x 4 iters = 32 tb
    const float* Ep = EgT + ((size_t)(b * 32 + tb) * 128) * 64 + lane;
    float s0 = 0.f, s1 = 0.f, s2 = 0.f, s3 = 0.f;
    for (int kc = 0; kc < 16; ++kc) {          // 8 k per chunk
      const float* ep = Ep + kc * 512;
      float ek[8];
      #pragma unroll
      for (int q = 0; q < 8; ++q) ek[q] = ep[q * 64];   // imm offsets 0..1792 B
      float4 v0 = vp[kc * 2], v1 = vp[kc * 2 + 1];
      const float4* fp = Fp + kc * 2;
      #pragma unroll
      for (int j = 0; j < 4; ++j) {
        float4 f0 = fp[j * 32];                // imm offsets j*512 B
        float4 f1 = fp[j * 32 + 1];
        float a;
        a  = v0.x * __builtin_amdgcn_rcpf(fmaf(ek[0], f0.x, 1.0f));
        a += v0.y * __builtin_amdgcn_rcpf(fmaf(ek[1], f0.y, 1.0f));
        a += v0.z * __builtin_amdgcn_rcpf(fmaf(ek[2], f0.z, 1.0f));
        a += v0.w * __builtin_amdgcn_rcpf(fmaf(ek[3], f0.w, 1.0f));
        a += v1.x * __builtin_amdgcn_rcpf(fmaf(ek[4], f1.x, 1.0f));
        a += v1.y * __builtin_amdgcn_rcpf(fmaf(ek[5], f1.y, 1.0f));
        a += v1.z * __builtin_amdgcn_rcpf(fmaf(ek[6], f1.z, 1.0f));
        a += v1.w * __builtin_amdgcn_rcpf(fmaf(ek[7], f1.w, 1.0f));
        if (j == 0) s0 += a; else if (j == 1) s1 += a; else if (j == 2) s2 += a; else s3 += a;
      }
    }
    int t = tb * 64 + lane;
    S[0 * 2048 + t] = V1 - 2.0f * s0;          // bank = lane%32: 2-way (free)
    S[1 * 2048 + t] = V1 - 2.0f * s1;
    S[2 * 2048 + t] = V1 - 2.0f * s2;
    S[3 * 2048 + t] = V1 - 2.0f * s3;
  }
  __syncthreads();

  // ---- phase 2: softmax per j-row (2 waves per j), e -> d_out + S2[t][4j] ----
  int j = w >> 1, half = w & 1;
  int tb2 = half * 1024 + lane;
  float x[16];
  #pragma unroll
  for (int q = 0; q < 16; ++q) x[q] = S[j * 2048 + tb2 + q * 64];
  float m = x[0];
  #pragma unroll
  for (int q = 1; q < 16; ++q) m = fmaxf(m, x[q]);
  #pragma unroll
  for (int off = 32; off > 0; off >>= 1) m = fmaxf(m, __shfl_xor(m, off));
  if (lane == 0) red[w] = m;
  __syncthreads();                             // also: all raw-S reads complete
  m = fmaxf(red[j * 2], red[j * 2 + 1]);
  const float L2E = 1.4426950408889634f;
  float sum = 0.f;
  #pragma unroll
  for (int q = 0; q < 16; ++q) {
    x[q] = __builtin_amdgcn_exp2f((x[q] - m) * L2E);
    sum += x[q];
  }
  #pragma unroll
  for (int off = 32; off > 0; off >>= 1) sum += __shfl_xor(sum, off);
  if (lane == 0) red[8 + w] = sum;
  __syncthreads();
  float inv = 1.0f / (red[8 + j * 2] + red[8 + j * 2 + 1]);
  float* orow = oute + (size_t)(b * TD + j0 + j) * TE;
  #pragma unroll
  for (int q = 0; q < 16; ++q) {
    float e = x[q] * inv;
    int t = tb2 + q * 64;
    orow[t] = e;                               // coalesced 256 B/instr
    S[t * 4 + j] = e;                          // S re-viewed as [t][4j]
  }
  __syncthreads();

  // ---- phase 3: c[j][h] = sum_t e[j][t]*enc[t][h]; 16 t-slices, LDS-combined ----
  int hq = tid & 31, slice = tid >> 5;         // h = hq*4; t in [slice*128, slice*128+128)
  const float* encp = enc + ((size_t)b * TE + slice * 128) * H + hq * 4;
  float4 acc0{0,0,0,0}, acc1{0,0,0,0}, acc2{0,0,0,0}, acc3{0,0,0,0};
  #pragma unroll 4
  for (int t = 0; t < 128; ++t) {
    float4 ev = *(const float4*)(encp + (size_t)t * H);          // 1 KB/wave-instr
    float4 e4 = *(const float4*)&S[(slice * 128 + t) * 4];       // b128 broadcast
    acc0.x += e4.x * ev.x; acc0.y += e4.x * ev.y; acc0.z += e4.x * ev.z; acc0.w += e4.x * ev.w;
    acc1.x += e4.y * ev.x; acc1.y += e4.y * ev.y; acc1.z += e4.y * ev.z; acc1.w += e4.y * ev.w;
    acc2.x += e4.z * ev.x; acc2.y += e4.z * ev.y; acc2.z += e4.z * ev.z; acc2.w += e4.z * ev.w;
    acc3.x += e4.w * ev.x; acc3.y += e4.w * ev.y; acc3.z += e4.w * ev.z; acc3.w += e4.w * ev.w;
  }
  __syncthreads();                             // all e-reads done; reuse S for partials
  *(float4*)&S[slice * 512 + 0 * 128 + hq * 4] = acc0;
  *(float4*)&S[slice * 512 + 1 * 128 + hq * 4] = acc1;
  *(float4*)&S[slice * 512 + 2 * 128 + hq * 4] = acc2;
  *(float4*)&S[slice * 512 + 3 * 128 + hq * 4] = acc3;
  __syncthreads();
  float r = 0.f;
  #pragma unroll
  for (int sl = 0; sl < 16; ++sl) r += S[sl * 512 + tid];        // conflict-free
  outc[(size_t)(b * TD + j0 + (tid >> 7)) * H + (tid & 127)] = r;
}

extern "C" void kernel_launch(void* const* d_in, const int* in_sizes, int n_in,
                              void* d_out, int out_size, void* d_ws, size_t ws_size,
                              hipStream_t stream) {
  (void)in_sizes; (void)n_in; (void)out_size; (void)ws_size;
  const float* enc = (const float*)d_in[0];
  const float* dec = (const float*)d_in[1];
  const float* Wa  = (const float*)d_in[2];
  const float* Ua  = (const float*)d_in[3];
  const float* Va  = (const float*)d_in[4];

  float* ws  = (float*)d_ws;
  float* EgT = ws;                                   // 2,097,152 f32 (8 MB)  E tiled [b][tb][k][tl]
  float* Fg  = EgT + (size_t)B * TE * H;             //   262,144 f32 (1 MB)  F [b][j][k]
  float* outc = (float*)d_out;                       // c [B,TD,H] fp32
  float* oute = outc + (size_t)B * TD * H;           // e [B,TD,TE] fp32

  proj_kernel<<<dim3(576), 256, 0, stream>>>(enc, dec, Wa, Ua, EgT, Fg);
  fused_kernel<<<dim3(64, 8), 512, 0, stream>>>(EgT, Fg, Va, enc, oute, outc);
}